// Round 8
// baseline (573.922 us; speedup 1.0000x reference)
//
#include <hip/hip_runtime.h>
#include <hip/hip_bf16.h>

typedef __attribute__((ext_vector_type(8))) short short8;
typedef __attribute__((ext_vector_type(4))) float floatx4;
typedef __attribute__((ext_vector_type(4))) unsigned int uintx4;

#define D_MODEL 1024
#define T_SEQ   2048
#define N_HEAD  16
#define NEG_BIG (-1e30f)
#define BK 32
#define LDSP 40 // fallback-gemm pitch
#define VP 72   // attention V-tile pitch: 144B rows (16B aligned), conflict-free b128
#define PP 72   // attention P-tile pitch

static __device__ __forceinline__ float bf2f(ushort u) {
  unsigned int x = ((unsigned int)u) << 16;
  return __builtin_bit_cast(float, x);
}
static __device__ __forceinline__ ushort san(ushort u) {
  return ((u & 0x7F80u) == 0x7F80u) ? (ushort)0 : u;
}
static __device__ __forceinline__ float bf2f_s(ushort u) { return bf2f(san(u)); }
static __device__ __forceinline__ ushort f2bf(float f) {
  unsigned int x = __builtin_bit_cast(unsigned int, f);
  x += 0x7FFFu + ((x >> 16) & 1u);
  return (ushort)(x >> 16);
}
static __device__ __forceinline__ float ext_ld(const void* p, size_t i, int isbf) {
  return isbf ? bf2f_s(((const ushort*)p)[i]) : ((const float*)p)[i];
}
// async global->LDS DMA, 16 B/lane; LDS dest = wave-uniform base + lane*16
static __device__ __forceinline__ void gload16(const void* g, void* l) {
  __builtin_amdgcn_global_load_lds(
      (const __attribute__((address_space(1))) void*)g,
      (__attribute__((address_space(3))) void*)l, 16, 0, 0);
}

// dtype probe: low ushort of dword -> bf16 data has exp in [0x60,0x8F] ~100%
__global__ void detect_dtype(const ushort* x, uint* flag) {
  int tid = threadIdx.x;
  int cnt = 0;
  for (int j = 0; j < 16; j++) {
    ushort u = x[2 * (tid * 16 + j)];
    int e = (u >> 7) & 0xFF;
    if (e >= 0x60 && e <= 0x8F) cnt++;
  }
  for (int d = 32; d; d >>= 1) cnt += __shfl_xor(cnt, d, 64);
  __shared__ int c[4];
  if ((tid & 63) == 0) c[tid >> 6] = cnt;
  __syncthreads();
  if (tid == 0) flag[0] = (c[0] + c[1] + c[2] + c[3] >= 2048) ? 1u : 0u;
}

// weight convert+transpose: in[R,C] (ext dtype) -> out[C,R] bf16
__global__ __launch_bounds__(256) void wconv(
    const void* __restrict__ in, ushort* __restrict__ out, int R, int C,
    const uint* __restrict__ flagp) {
  int isbf = (int)*flagp;
  __shared__ float t[32][33];
  int tx = threadIdx.x & 31, ty = threadIdx.x >> 5;
  int c0 = blockIdx.x * 32, r0 = blockIdx.y * 32;
  for (int i = ty; i < 32; i += 8)
    t[i][tx] = ext_ld(in, (size_t)(r0 + i) * C + c0 + tx, isbf);
  __syncthreads();
  for (int i = ty; i < 32; i += 8)
    out[(size_t)(c0 + i) * R + r0 + tx] = f2bf(t[tx][i]);
}

// ---------------- LayerNorm -> bf16 ----------------
__global__ __launch_bounds__(256) void ln_kernel(
    const void* __restrict__ x, const void* __restrict__ g,
    const void* __restrict__ bb, ushort* __restrict__ out,
    int ext, const uint* __restrict__ flagp) {
  int wbf = (int)*flagp;
  int xbf = ext ? wbf : 1;
  int row = blockIdx.x, tid = threadIdx.x;
  size_t ro = (size_t)row * D_MODEL;
  float v[4], gv[4], bv[4];
  if (!xbf) {
    floatx4 xv = *((const floatx4*)((const float*)x + ro) + tid);
#pragma unroll
    for (int i = 0; i < 4; i++) v[i] = xv[i];
  } else {
#pragma unroll
    for (int i = 0; i < 4; i++) v[i] = bf2f_s(((const ushort*)x)[ro + tid * 4 + i]);
  }
  float s = 0.f, sq = 0.f;
#pragma unroll
  for (int i = 0; i < 4; i++) { s += v[i]; sq += v[i] * v[i]; }
#pragma unroll
  for (int d = 32; d; d >>= 1) {
    s += __shfl_xor(s, d, 64);
    sq += __shfl_xor(sq, d, 64);
  }
  __shared__ float red[8];
  int wave = tid >> 6, lane = tid & 63;
  if (lane == 0) { red[wave] = s; red[4 + wave] = sq; }
  __syncthreads();
  s = red[0] + red[1] + red[2] + red[3];
  sq = red[4] + red[5] + red[6] + red[7];
  float mu = s * (1.0f / D_MODEL);
  float var = sq * (1.0f / D_MODEL) - mu * mu;
  float rs = rsqrtf(fmaxf(var, 0.f) + 1e-5f);
  if (!wbf) {
    floatx4 g4 = *((const floatx4*)g + tid);
    floatx4 b4 = *((const floatx4*)bb + tid);
#pragma unroll
    for (int i = 0; i < 4; i++) { gv[i] = g4[i]; bv[i] = b4[i]; }
  } else {
#pragma unroll
    for (int i = 0; i < 4; i++) {
      gv[i] = bf2f_s(((const ushort*)g)[tid * 4 + i]);
      bv[i] = bf2f_s(((const ushort*)bb)[tid * 4 + i]);
    }
  }
  ushort o4[4];
#pragma unroll
  for (int i = 0; i < 4; i++) o4[i] = f2bf((v[i] - mu) * rs * gv[i] + bv[i]);
  *(uint2*)(out + ro + tid * 4) = *(uint2*)o4;
}

// ---------------- fast GEMM: C = A[M,K] @ Bt[N,K]^T, both bf16 --------------
// global_load_lds(16B) staging into UNPADDED [128][32] LDS tiles.
// EPI: 0 plain bf16 | 1 +res(ext) bf16 | 2 +bias(ext)+GELU bf16 |
//      5 +bias(ext)+res(bf16) -> store FINAL dtype
// SPLIT: N=3072 QKV; C0/C1/C2 segments of 1024 cols.
template <int EPI, int SPLIT>
__global__ __launch_bounds__(256) void gemm_tt(
    const ushort* __restrict__ A, int lda,
    const ushort* __restrict__ Bt, int ldbt,
    void* __restrict__ C0v, ushort* __restrict__ C1, ushort* __restrict__ C2,
    int ldc,
    const void* __restrict__ bias, size_t biasoff,
    const void* __restrict__ res, int ldr,
    int M, int K, const uint* __restrict__ flagp) {
  __shared__ __align__(16) ushort As[128 * 32];
  __shared__ __align__(16) ushort Bs[128 * 32];
  int isbf = (int)*flagp;
  int tid = threadIdx.x;
  int wave = tid >> 6, lane = tid & 63, lm = lane & 15, quad = lane >> 4;
  int m0 = blockIdx.x * 128, n0 = blockIdx.y * 128;
  int wm = (wave >> 1) * 64, wn = (wave & 1) * 64;
  floatx4 acc[4][4] = {};
  int sr = tid >> 2;
  int sc = (tid & 3) * 8;
  ushort* lA0 = &As[(wave * 16) * 32];
  ushort* lA1 = &As[(64 + wave * 16) * 32];
  ushort* lB0 = &Bs[(wave * 16) * 32];
  ushort* lB1 = &Bs[(64 + wave * 16) * 32];

  for (int kk = 0; kk < K; kk += BK) {
    gload16(A + (size_t)(m0 + sr) * lda + kk + sc, lA0);
    gload16(A + (size_t)(m0 + sr + 64) * lda + kk + sc, lA1);
    gload16(Bt + (size_t)(n0 + sr) * ldbt + kk + sc, lB0);
    gload16(Bt + (size_t)(n0 + sr + 64) * ldbt + kk + sc, lB1);
    __syncthreads();
    short8 af[4], bf[4];
#pragma unroll
    for (int i = 0; i < 4; i++)
      af[i] = *(const short8*)&As[(wm + i * 16 + lm) * 32 + quad * 8];
#pragma unroll
    for (int i = 0; i < 4; i++)
      bf[i] = *(const short8*)&Bs[(wn + i * 16 + lm) * 32 + quad * 8];
#pragma unroll
    for (int mi = 0; mi < 4; mi++)
#pragma unroll
      for (int ni = 0; ni < 4; ni++)
        acc[mi][ni] = __builtin_amdgcn_mfma_f32_16x16x32_bf16(
            af[mi], bf[ni], acc[mi][ni], 0, 0, 0);
    __syncthreads();
  }

  ushort* Cseg = (ushort*)C0v;
  int colbase = n0;
  if (SPLIT) {
    int seg = n0 >> 10;
    Cseg = (seg == 0) ? (ushort*)C0v : (seg == 1 ? C1 : C2);
    colbase = n0 & 1023;
  }
#pragma unroll
  for (int mi = 0; mi < 4; mi++) {
#pragma unroll
    for (int ni = 0; ni < 4; ni++) {
      int col = colbase + wn + ni * 16 + lm;
#pragma unroll
      for (int r = 0; r < 4; r++) {
        int row = m0 + wm + mi * 16 + quad * 4 + r;
        size_t ci = (size_t)row * ldc + col;
        float v = acc[mi][ni][r];
        if (EPI == 2 || EPI == 5) v += ext_ld(bias, biasoff + col, isbf);
        if (EPI == 1) v += ext_ld(res, (size_t)row * ldr + col, isbf);
        if (EPI == 5) v += bf2f(((const ushort*)res)[(size_t)row * ldr + col]);
        if (EPI == 2) v = 0.5f * v * (1.0f + erff(v * 0.70710678118654752f));
        if (EPI == 5 && !isbf) ((float*)C0v)[ci] = v;
        else                   Cseg[ci] = f2bf(v);
      }
    }
  }
}

// ---------------- fallback GEMM (R5-proven): B in [K,N] external dtype ------
template <int EPI, int FINAL>
__global__ __launch_bounds__(256) void gemm_kn(
    const ushort* __restrict__ A, int lda,
    const void* __restrict__ B, int ldb, size_t boff,
    void* __restrict__ C, int ldc,
    const void* __restrict__ bias, size_t biasoff,
    const void* __restrict__ res, int ldr,
    int M, int K, const uint* __restrict__ flagp) {
  __shared__ __align__(16) ushort As[128 * LDSP];
  __shared__ __align__(16) ushort Bs[128 * LDSP];
  int isbf = (int)*flagp;
  int tid = threadIdx.x;
  int wave = tid >> 6, lane = tid & 63, lm = lane & 15, quad = lane >> 4;
  int m0 = blockIdx.x * 128, n0 = blockIdx.y * 128;
  int wm = (wave >> 1) * 64, wn = (wave & 1) * 64;
  floatx4 acc[4][4] = {};
  int sr = tid >> 2;
  int sc = (tid & 3) * 8;
  int bk = tid >> 4;
  int bn8 = (tid & 15) * 8;

  for (int kk = 0; kk < K; kk += BK) {
    uintx4 va0 = *(const uintx4*)(A + (size_t)(m0 + sr) * lda + kk + sc);
    uintx4 va1 = *(const uintx4*)(A + (size_t)(m0 + sr + 64) * lda + kk + sc);
    *(uintx4*)&As[sr * LDSP + sc] = va0;
    *(uintx4*)&As[(sr + 64) * LDSP + sc] = va1;
    if (isbf) {
      const ushort* Bu = (const ushort*)B;
#pragma unroll
      for (int p = 0; p < 2; p++) {
        int krow = bk + p * 16;
        uintx4 raw = *(const uintx4*)(Bu + boff + (size_t)(kk + krow) * ldb + n0 + bn8);
        ushort tmp[8] __attribute__((aligned(16)));
        *(uintx4*)tmp = raw;
#pragma unroll
        for (int i = 0; i < 8; i++) Bs[(bn8 + i) * LDSP + krow] = san(tmp[i]);
      }
    } else {
      const float* Bf = (const float*)B;
#pragma unroll
      for (int p = 0; p < 2; p++) {
        int krow = bk + p * 16;
        const float* src = Bf + boff + (size_t)(kk + krow) * ldb + n0 + bn8;
        floatx4 f0 = *(const floatx4*)src;
        floatx4 f1 = *(const floatx4*)(src + 4);
#pragma unroll
        for (int i = 0; i < 4; i++) {
          Bs[(bn8 + i) * LDSP + krow] = f2bf(f0[i]);
          Bs[(bn8 + 4 + i) * LDSP + krow] = f2bf(f1[i]);
        }
      }
    }
    __syncthreads();
    short8 af[4], bf[4];
#pragma unroll
    for (int i = 0; i < 4; i++)
      af[i] = *(const short8*)&As[(wm + i * 16 + lm) * LDSP + quad * 8];
#pragma unroll
    for (int i = 0; i < 4; i++)
      bf[i] = *(const short8*)&Bs[(wn + i * 16 + lm) * LDSP + quad * 8];
#pragma unroll
    for (int mi = 0; mi < 4; mi++)
#pragma unroll
      for (int ni = 0; ni < 4; ni++)
        acc[mi][ni] = __builtin_amdgcn_mfma_f32_16x16x32_bf16(
            af[mi], bf[ni], acc[mi][ni], 0, 0, 0);
    __syncthreads();
  }

#pragma unroll
  for (int mi = 0; mi < 4; mi++) {
#pragma unroll
    for (int ni = 0; ni < 4; ni++) {
      int col = n0 + wn + ni * 16 + lm;
#pragma unroll
      for (int r = 0; r < 4; r++) {
        int row = m0 + wm + mi * 16 + quad * 4 + r;
        size_t ci = (size_t)row * ldc + col;
        float v = acc[mi][ni][r];
        if (EPI == 4)
          v += (FINAL && !isbf) ? ((const float*)C)[ci] : bf2f(((const ushort*)C)[ci]);
        if (EPI == 2 || EPI == 4) v += ext_ld(bias, biasoff + col, isbf);
        if (EPI == 1) v += ext_ld(res, (size_t)row * ldr + col, isbf);
        if (EPI == 4) v += bf2f(((const ushort*)res)[(size_t)row * ldr + col]);
        if (EPI == 2) v = 0.5f * v * (1.0f + erff(v * 0.70710678118654752f));
        if (FINAL && !isbf) ((float*)C)[ci] = v;
        else                ((ushort*)C)[ci] = f2bf(v);
      }
    }
  }
}

// ---------------- causal flash attention: barrier-free, per-wave LDS --------
// Each wave: 16 queries, private V-tile + P buffers. NO __syncthreads.
// Intra-wave LDS write->read ordered by compiler lgkmcnt (wave-synchronous).
__global__ __launch_bounds__(256) void attn_kernel(
    const ushort* __restrict__ q, const ushort* __restrict__ k,
    const ushort* __restrict__ v, ushort* __restrict__ ctx) {
  int tid = threadIdx.x, wave = tid >> 6, lane = tid & 63;
  int lm = lane & 15, quad = lane >> 4;
  int bx = blockIdx.x, h = blockIdx.y, b = blockIdx.z;
  int qt = (bx & 1) ? (31 - (bx >> 1)) : (bx >> 1);  // zig-zag balance
  int qw = qt * 64 + wave * 16;
  size_t base = (size_t)b * T_SEQ * D_MODEL + h * 64;

  __shared__ __align__(16) ushort VstAll[4][64 * VP];  // per-wave V^T tile
  __shared__ __align__(16) ushort PlAll[4][16 * PP];   // per-wave P tile
  ushort* Vst = VstAll[wave];
  ushort* Pl = PlAll[wave];

  short8 aq0 = *(const short8*)&q[base + (size_t)(qw + lm) * D_MODEL + quad * 8];
  short8 aq1 = *(const short8*)&q[base + (size_t)(qw + lm) * D_MODEL + 32 + quad * 8];

  floatx4 O[4] = {};
  float mr[4], lr[4];
#pragma unroll
  for (int r = 0; r < 4; r++) { mr[r] = NEG_BIG; lr[r] = 0.f; }

  int ntiles = qt + 1;
  for (int kt = 0; kt < ntiles; ++kt) {
    int k0 = kt * 64;
    // V tile: lane loads its own key-row (64 cols), scatters transposed
    const ushort* vr = &v[base + (size_t)(k0 + lane) * D_MODEL];
    uintx4 vv[8];
#pragma unroll
    for (int c = 0; c < 8; c++) vv[c] = *(const uintx4*)(vr + c * 8);
    // K frags + QK^T
    floatx4 sc[4];
#pragma unroll
    for (int g = 0; g < 4; g++) {
      const ushort* kr = &k[base + (size_t)(k0 + g * 16 + lm) * D_MODEL + quad * 8];
      short8 bka = *(const short8*)kr;
      short8 bkb = *(const short8*)(kr + 32);
      floatx4 z = {};
      sc[g] = __builtin_amdgcn_mfma_f32_16x16x32_bf16(aq0, bka, z, 0, 0, 0);
      sc[g] = __builtin_amdgcn_mfma_f32_16x16x32_bf16(aq1, bkb, sc[g], 0, 0, 0);
    }
    // scatter V^T into private LDS (conflict-free: fixed col, lanes consecutive)
#pragma unroll
    for (int c = 0; c < 8; c++) {
      ushort t[8] __attribute__((aligned(16)));
      *(uintx4*)t = vv[c];
#pragma unroll
      for (int i = 0; i < 8; i++) Vst[(c * 8 + i) * VP + lane] = t[i];
    }
    // online softmax
    bool full = (k0 + 63 <= qw);
#pragma unroll
    for (int r = 0; r < 4; r++) {
      int qrow = qw + quad * 4 + r;
      float a[4];
#pragma unroll
      for (int g = 0; g < 4; g++) {
        a[g] = sc[g][r] * 0.125f;
        if (!full && (k0 + g * 16 + lm > qrow)) a[g] = NEG_BIG;
      }
      float tm = fmaxf(fmaxf(a[0], a[1]), fmaxf(a[2], a[3]));
#pragma unroll
      for (int d = 1; d < 16; d <<= 1) tm = fmaxf(tm, __shfl_xor(tm, d, 64));
      float mn = fmaxf(mr[r], tm);
      float alpha = __expf(mr[r] - mn);
      float p[4], rsum = 0.f;
#pragma unroll
      for (int g = 0; g < 4; g++) { p[g] = __expf(a[g] - mn); rsum += p[g]; }
#pragma unroll
      for (int d = 1; d < 16; d <<= 1) rsum += __shfl_xor(rsum, d, 64);
      mr[r] = mn;
      lr[r] = lr[r] * alpha + rsum;
      O[0][r] *= alpha; O[1][r] *= alpha; O[2][r] *= alpha; O[3][r] *= alpha;
#pragma unroll
      for (int g = 0; g < 4; g++)
        Pl[(quad * 4 + r) * PP + g * 16 + lm] = f2bf(p[g]);
    }
    // P (A-layout) + V frags (B-layout) -> PV
    short8 pa0 = *(const short8*)&Pl[lm * PP + quad * 8];
    short8 pa1 = *(const short8*)&Pl[lm * PP + 32 + quad * 8];
#pragma unroll
    for (int d4 = 0; d4 < 4; d4++) {
      short8 bv0 = *(const short8*)&Vst[(d4 * 16 + lm) * VP + quad * 8];
      short8 bv1 = *(const short8*)&Vst[(d4 * 16 + lm) * VP + 32 + quad * 8];
      O[d4] = __builtin_amdgcn_mfma_f32_16x16x32_bf16(pa0, bv0, O[d4], 0, 0, 0);
      O[d4] = __builtin_amdgcn_mfma_f32_16x16x32_bf16(pa1, bv1, O[d4], 0, 0, 0);
    }
  }
#pragma unroll
  for (int d4 = 0; d4 < 4; d4++)
#pragma unroll
    for (int r = 0; r < 4; r++) {
      float val = O[d4][r] / fmaxf(lr[r], 1e-20f);
      ctx[base + (size_t)(qw + quad * 4 + r) * D_MODEL + d4 * 16 + lm] = f2bf(val);
    }
}

// ---------------------------------------------------------------------------
extern "C" void kernel_launch(void* const* d_in, const int* in_sizes, int n_in,
                              void* d_out, int out_size, void* d_ws, size_t ws_size,
                              hipStream_t stream) {
  const void* x     = d_in[0];
  const void* ln1_g = d_in[1];
  const void* ln1_b = d_in[2];
  const void* Wq    = d_in[3];
  const void* Wk    = d_in[4];
  const void* Wv    = d_in[5];
  const void* Wo    = d_in[6];
  const void* ln2_g = d_in[7];
  const void* ln2_b = d_in[8];
  const void* W1    = d_in[9];
  const void* b1    = d_in[10];
  const void* W2    = d_in[11];
  const void* b2    = d_in[12];

  const int M = 2 * T_SEQ;  // 4096
  const size_t MEG = 1024 * 1024;
  ushort* W = (ushort*)d_ws;
  ushort* Abuf = W;             // h1 -> ctx -> h2
  ushort* kbuf = W + 4 * MEG;   // k -> x2
  ushort* vbuf = W + 8 * MEG;   // v -> act (act spans 8M..16M in fast path)
  ushort* qbuf = (ushort*)d_out;

  dim3 blk(256);
  dim3 g18(32, 8);
  dim3 attng(T_SEQ / 64, N_HEAD, 2);

  bool fast = ws_size >= (size_t)40 * MEG + 4096;

  if (fast) {
    ushort* WqkvT = W + 12 * MEG;             // [3072,1024] (dead after QKV)
    ushort* WoT   = W + 15 * MEG;             // [1024,1024] (dead after Wo)
    ushort* W1T   = W + 16 * MEG;             // [2048,1024]
    ushort* W2T   = W + 18 * MEG;             // [1024,2048]
    ushort* act   = W + 8 * MEG;              // [4096,2048] over v/WqkvT/WoT
    uint* flag = (uint*)(W + 20 * MEG);

    detect_dtype<<<1, 256, 0, stream>>>((const ushort*)x, flag);

    wconv<<<dim3(32, 32), blk, 0, stream>>>(Wq, WqkvT, 1024, 1024, flag);
    wconv<<<dim3(32, 32), blk, 0, stream>>>(Wk, WqkvT + 1 * MEG, 1024, 1024, flag);
    wconv<<<dim3(32, 32), blk, 0, stream>>>(Wv, WqkvT + 2 * MEG, 1024, 1024, flag);
    wconv<<<dim3(32, 32), blk, 0, stream>>>(Wo, WoT, 1024, 1024, flag);
    wconv<<<dim3(64, 32), blk, 0, stream>>>(W1, W1T, 1024, 2048, flag);
    wconv<<<dim3(32, 64), blk, 0, stream>>>(W2, W2T, 2048, 1024, flag);

    ln_kernel<<<dim3(M), blk, 0, stream>>>(x, ln1_g, ln1_b, Abuf, 1, flag);

    gemm_tt<0, 1><<<dim3(32, 24), blk, 0, stream>>>(
        Abuf, 1024, WqkvT, 1024, qbuf, kbuf, vbuf, 1024,
        nullptr, 0, nullptr, 0, M, 1024, flag);

    attn_kernel<<<attng, blk, 0, stream>>>(qbuf, kbuf, vbuf, Abuf);

    gemm_tt<1, 0><<<g18, blk, 0, stream>>>(
        Abuf, 1024, WoT, 1024, kbuf, nullptr, nullptr, 1024,
        nullptr, 0, x, 1024, M, 1024, flag);

    ln_kernel<<<dim3(M), blk, 0, stream>>>(kbuf, ln2_g, ln2_b, Abuf, 0, flag);

    // MLP full-width: h2 @ W1 (+b1, GELU) -> act[4096,2048]
    gemm_tt<2, 0><<<dim3(32, 16), blk, 0, stream>>>(
        Abuf, 1024, W1T, 1024, act, nullptr, nullptr, 2048,
        b1, 0, nullptr, 0, M, 1024, flag);
    // act @ W2 + b2 + x2 -> d_out (fp32), K=2048
    gemm_tt<5, 0><<<g18, blk, 0, stream>>>(
        act, 2048, W2T, 2048, d_out, nullptr, nullptr, 1024,
        b2, 0, kbuf, 1024, M, 2048, flag);
  } else {
    uint* flag = (uint*)(W + 12 * MEG);
    detect_dtype<<<1, 256, 0, stream>>>((const ushort*)x, flag);
    ln_kernel<<<dim3(M), blk, 0, stream>>>(x, ln1_g, ln1_b, Abuf, 1, flag);
    gemm_kn<0, 0><<<g18, blk, 0, stream>>>(Abuf, 1024, Wq, 1024, 0, qbuf, 1024,
                                           nullptr, 0, nullptr, 0, M, 1024, flag);
    gemm_kn<0, 0><<<g18, blk, 0, stream>>>(Abuf, 1024, Wk, 1024, 0, kbuf, 1024,
                                           nullptr, 0, nullptr, 0, M, 1024, flag);
    gemm_kn<0, 0><<<g18, blk, 0, stream>>>(Abuf, 1024, Wv, 1024, 0, vbuf, 1024,
                                           nullptr, 0, nullptr, 0, M, 1024, flag);
    attn_kernel<<<attng, blk, 0, stream>>>(qbuf, kbuf, vbuf, Abuf);
    gemm_kn<1, 0><<<g18, blk, 0, stream>>>(Abuf, 1024, Wo, 1024, 0, kbuf, 1024,
                                           nullptr, 0, x, 1024, M, 1024, flag);
    ln_kernel<<<dim3(M), blk, 0, stream>>>(kbuf, ln2_g, ln2_b, Abuf, 0, flag);
    gemm_kn<2, 0><<<g18, blk, 0, stream>>>(Abuf, 1024, W1, 2048, 0, vbuf, 1024,
                                           b1, 0, nullptr, 0, M, 1024, flag);
    gemm_kn<0, 1><<<g18, blk, 0, stream>>>(vbuf, 1024, W2, 1024, 0, d_out, 1024,
                                           nullptr, 0, nullptr, 0, M, 1024, flag);
    gemm_kn<2, 0><<<g18, blk, 0, stream>>>(Abuf, 1024, W1, 2048, 1024, vbuf, 1024,
                                           b1, 1024, nullptr, 0, M, 1024, flag);
    gemm_kn<4, 1><<<g18, blk, 0, stream>>>(vbuf, 1024, W2, 1024, (size_t)1024 * 1024,
                                           d_out, 1024, b2, 0, kbuf, 1024, M, 1024, flag);
  }
}

// Round 9
// 548.115 us; speedup vs baseline: 1.0471x; 1.0471x over previous
//
#include <hip/hip_runtime.h>
#include <hip/hip_bf16.h>

typedef __attribute__((ext_vector_type(8))) short short8;
typedef __attribute__((ext_vector_type(4))) float floatx4;
typedef __attribute__((ext_vector_type(4))) unsigned int uintx4;

#define D_MODEL 1024
#define T_SEQ   2048
#define N_HEAD  16
#define NEG_BIG (-1e30f)
#define BK 32
#define LDSP 40 // fallback-gemm pitch
#define PP 72   // attention P-tile pitch

static __device__ __forceinline__ float bf2f(ushort u) {
  unsigned int x = ((unsigned int)u) << 16;
  return __builtin_bit_cast(float, x);
}
static __device__ __forceinline__ ushort san(ushort u) {
  return ((u & 0x7F80u) == 0x7F80u) ? (ushort)0 : u;
}
static __device__ __forceinline__ float bf2f_s(ushort u) { return bf2f(san(u)); }
static __device__ __forceinline__ ushort f2bf(float f) {
  unsigned int x = __builtin_bit_cast(unsigned int, f);
  x += 0x7FFFu + ((x >> 16) & 1u);
  return (ushort)(x >> 16);
}
static __device__ __forceinline__ float ext_ld(const void* p, size_t i, int isbf) {
  return isbf ? bf2f_s(((const ushort*)p)[i]) : ((const float*)p)[i];
}
// async global->LDS DMA, 16 B/lane; LDS dest = wave-uniform base + lane*16
static __device__ __forceinline__ void gload16(const void* g, void* l) {
  __builtin_amdgcn_global_load_lds(
      (const __attribute__((address_space(1))) void*)g,
      (__attribute__((address_space(3))) void*)l, 16, 0, 0);
}

// dtype probe: low ushort of dword -> bf16 data has exp in [0x60,0x8F] ~100%
__global__ void detect_dtype(const ushort* x, uint* flag) {
  int tid = threadIdx.x;
  int cnt = 0;
  for (int j = 0; j < 16; j++) {
    ushort u = x[2 * (tid * 16 + j)];
    int e = (u >> 7) & 0xFF;
    if (e >= 0x60 && e <= 0x8F) cnt++;
  }
  for (int d = 32; d; d >>= 1) cnt += __shfl_xor(cnt, d, 64);
  __shared__ int c[4];
  if ((tid & 63) == 0) c[tid >> 6] = cnt;
  __syncthreads();
  if (tid == 0) flag[0] = (c[0] + c[1] + c[2] + c[3] >= 2048) ? 1u : 0u;
}

// weight convert+transpose: in[R,C] (ext dtype) -> out[C,R] bf16
__global__ __launch_bounds__(256) void wconv(
    const void* __restrict__ in, ushort* __restrict__ out, int R, int C,
    const uint* __restrict__ flagp) {
  int isbf = (int)*flagp;
  __shared__ float t[32][33];
  int tx = threadIdx.x & 31, ty = threadIdx.x >> 5;
  int c0 = blockIdx.x * 32, r0 = blockIdx.y * 32;
  for (int i = ty; i < 32; i += 8)
    t[i][tx] = ext_ld(in, (size_t)(r0 + i) * C + c0 + tx, isbf);
  __syncthreads();
  for (int i = ty; i < 32; i += 8)
    out[(size_t)(c0 + i) * R + r0 + tx] = f2bf(t[tx][i]);
}

// V transpose per head: v[B*T, D] (head h cols) -> vT[(b*16+h)*64 + hd][t]
__global__ __launch_bounds__(256) void vtrans(
    const ushort* __restrict__ v, ushort* __restrict__ vT) {
  __shared__ ushort t[32][33];
  int tx = threadIdx.x & 31, ty = threadIdx.x >> 5;
  int t0 = blockIdx.x * 32;          // token tile
  int c0 = blockIdx.y * 32;          // hd tile (0 or 32)
  int bz = blockIdx.z;               // b*16 + h
  int b = bz >> 4, h = bz & 15;
  for (int i = ty; i < 32; i += 8)
    t[i][tx] = v[(size_t)(b * T_SEQ + t0 + i) * D_MODEL + h * 64 + c0 + tx];
  __syncthreads();
  for (int i = ty; i < 32; i += 8)
    vT[(size_t)(bz * 64 + c0 + i) * T_SEQ + t0 + tx] = t[tx][i];
}

// ---------------- LayerNorm -> bf16 ----------------
__global__ __launch_bounds__(256) void ln_kernel(
    const void* __restrict__ x, const void* __restrict__ g,
    const void* __restrict__ bb, ushort* __restrict__ out,
    int ext, const uint* __restrict__ flagp) {
  int wbf = (int)*flagp;
  int xbf = ext ? wbf : 1;
  int row = blockIdx.x, tid = threadIdx.x;
  size_t ro = (size_t)row * D_MODEL;
  float v[4], gv[4], bv[4];
  if (!xbf) {
    floatx4 xv = *((const floatx4*)((const float*)x + ro) + tid);
#pragma unroll
    for (int i = 0; i < 4; i++) v[i] = xv[i];
  } else {
#pragma unroll
    for (int i = 0; i < 4; i++) v[i] = bf2f_s(((const ushort*)x)[ro + tid * 4 + i]);
  }
  float s = 0.f, sq = 0.f;
#pragma unroll
  for (int i = 0; i < 4; i++) { s += v[i]; sq += v[i] * v[i]; }
#pragma unroll
  for (int d = 32; d; d >>= 1) {
    s += __shfl_xor(s, d, 64);
    sq += __shfl_xor(sq, d, 64);
  }
  __shared__ float red[8];
  int wave = tid >> 6, lane = tid & 63;
  if (lane == 0) { red[wave] = s; red[4 + wave] = sq; }
  __syncthreads();
  s = red[0] + red[1] + red[2] + red[3];
  sq = red[4] + red[5] + red[6] + red[7];
  float mu = s * (1.0f / D_MODEL);
  float var = sq * (1.0f / D_MODEL) - mu * mu;
  float rs = rsqrtf(fmaxf(var, 0.f) + 1e-5f);
  if (!wbf) {
    floatx4 g4 = *((const floatx4*)g + tid);
    floatx4 b4 = *((const floatx4*)bb + tid);
#pragma unroll
    for (int i = 0; i < 4; i++) { gv[i] = g4[i]; bv[i] = b4[i]; }
  } else {
#pragma unroll
    for (int i = 0; i < 4; i++) {
      gv[i] = bf2f_s(((const ushort*)g)[tid * 4 + i]);
      bv[i] = bf2f_s(((const ushort*)bb)[tid * 4 + i]);
    }
  }
  ushort o4[4];
#pragma unroll
  for (int i = 0; i < 4; i++) o4[i] = f2bf((v[i] - mu) * rs * gv[i] + bv[i]);
  *(uint2*)(out + ro + tid * 4) = *(uint2*)o4;
}

// ---------------- fast GEMM: C = A[M,K] @ Bt[N,K]^T, both bf16 --------------
// EPI: 0 plain bf16 | 1 +res(ext) bf16 | 2 +bias(ext)+GELU bf16 |
//      5 +bias(ext)+res(bf16) -> store FINAL dtype
template <int EPI, int SPLIT>
__global__ __launch_bounds__(256) void gemm_tt(
    const ushort* __restrict__ A, int lda,
    const ushort* __restrict__ Bt, int ldbt,
    void* __restrict__ C0v, ushort* __restrict__ C1, ushort* __restrict__ C2,
    int ldc,
    const void* __restrict__ bias, size_t biasoff,
    const void* __restrict__ res, int ldr,
    int M, int K, const uint* __restrict__ flagp) {
  __shared__ __align__(16) ushort As[128 * 32];
  __shared__ __align__(16) ushort Bs[128 * 32];
  int isbf = (int)*flagp;
  int tid = threadIdx.x;
  int wave = tid >> 6, lane = tid & 63, lm = lane & 15, quad = lane >> 4;
  int m0 = blockIdx.x * 128, n0 = blockIdx.y * 128;
  int wm = (wave >> 1) * 64, wn = (wave & 1) * 64;
  floatx4 acc[4][4] = {};
  int sr = tid >> 2;
  int sc = (tid & 3) * 8;
  ushort* lA0 = &As[(wave * 16) * 32];
  ushort* lA1 = &As[(64 + wave * 16) * 32];
  ushort* lB0 = &Bs[(wave * 16) * 32];
  ushort* lB1 = &Bs[(64 + wave * 16) * 32];

  for (int kk = 0; kk < K; kk += BK) {
    gload16(A + (size_t)(m0 + sr) * lda + kk + sc, lA0);
    gload16(A + (size_t)(m0 + sr + 64) * lda + kk + sc, lA1);
    gload16(Bt + (size_t)(n0 + sr) * ldbt + kk + sc, lB0);
    gload16(Bt + (size_t)(n0 + sr + 64) * ldbt + kk + sc, lB1);
    __syncthreads();
    short8 af[4], bf[4];
#pragma unroll
    for (int i = 0; i < 4; i++)
      af[i] = *(const short8*)&As[(wm + i * 16 + lm) * 32 + quad * 8];
#pragma unroll
    for (int i = 0; i < 4; i++)
      bf[i] = *(const short8*)&Bs[(wn + i * 16 + lm) * 32 + quad * 8];
#pragma unroll
    for (int mi = 0; mi < 4; mi++)
#pragma unroll
      for (int ni = 0; ni < 4; ni++)
        acc[mi][ni] = __builtin_amdgcn_mfma_f32_16x16x32_bf16(
            af[mi], bf[ni], acc[mi][ni], 0, 0, 0);
    __syncthreads();
  }

  ushort* Cseg = (ushort*)C0v;
  int colbase = n0;
  if (SPLIT) {
    int seg = n0 >> 10;
    Cseg = (seg == 0) ? (ushort*)C0v : (seg == 1 ? C1 : C2);
    colbase = n0 & 1023;
  }
#pragma unroll
  for (int mi = 0; mi < 4; mi++) {
#pragma unroll
    for (int ni = 0; ni < 4; ni++) {
      int col = colbase + wn + ni * 16 + lm;
#pragma unroll
      for (int r = 0; r < 4; r++) {
        int row = m0 + wm + mi * 16 + quad * 4 + r;
        size_t ci = (size_t)row * ldc + col;
        float v = acc[mi][ni][r];
        if (EPI == 2 || EPI == 5) v += ext_ld(bias, biasoff + col, isbf);
        if (EPI == 1) v += ext_ld(res, (size_t)row * ldr + col, isbf);
        if (EPI == 5) v += bf2f(((const ushort*)res)[(size_t)row * ldr + col]);
        if (EPI == 2) v = 0.5f * v * (1.0f + erff(v * 0.70710678118654752f));
        if (EPI == 5 && !isbf) ((float*)C0v)[ci] = v;
        else                   Cseg[ci] = f2bf(v);
      }
    }
  }
}

// ---------------- fallback GEMM: B in [K,N] external dtype ------------------
template <int EPI, int FINAL>
__global__ __launch_bounds__(256) void gemm_kn(
    const ushort* __restrict__ A, int lda,
    const void* __restrict__ B, int ldb, size_t boff,
    void* __restrict__ C, int ldc,
    const void* __restrict__ bias, size_t biasoff,
    const void* __restrict__ res, int ldr,
    int M, int K, const uint* __restrict__ flagp) {
  __shared__ __align__(16) ushort As[128 * LDSP];
  __shared__ __align__(16) ushort Bs[128 * LDSP];
  int isbf = (int)*flagp;
  int tid = threadIdx.x;
  int wave = tid >> 6, lane = tid & 63, lm = lane & 15, quad = lane >> 4;
  int m0 = blockIdx.x * 128, n0 = blockIdx.y * 128;
  int wm = (wave >> 1) * 64, wn = (wave & 1) * 64;
  floatx4 acc[4][4] = {};
  int sr = tid >> 2;
  int sc = (tid & 3) * 8;
  int bk = tid >> 4;
  int bn8 = (tid & 15) * 8;

  for (int kk = 0; kk < K; kk += BK) {
    uintx4 va0 = *(const uintx4*)(A + (size_t)(m0 + sr) * lda + kk + sc);
    uintx4 va1 = *(const uintx4*)(A + (size_t)(m0 + sr + 64) * lda + kk + sc);
    *(uintx4*)&As[sr * LDSP + sc] = va0;
    *(uintx4*)&As[(sr + 64) * LDSP + sc] = va1;
    if (isbf) {
      const ushort* Bu = (const ushort*)B;
#pragma unroll
      for (int p = 0; p < 2; p++) {
        int krow = bk + p * 16;
        uintx4 raw = *(const uintx4*)(Bu + boff + (size_t)(kk + krow) * ldb + n0 + bn8);
        ushort tmp[8] __attribute__((aligned(16)));
        *(uintx4*)tmp = raw;
#pragma unroll
        for (int i = 0; i < 8; i++) Bs[(bn8 + i) * LDSP + krow] = san(tmp[i]);
      }
    } else {
      const float* Bf = (const float*)B;
#pragma unroll
      for (int p = 0; p < 2; p++) {
        int krow = bk + p * 16;
        const float* src = Bf + boff + (size_t)(kk + krow) * ldb + n0 + bn8;
        floatx4 f0 = *(const floatx4*)src;
        floatx4 f1 = *(const floatx4*)(src + 4);
#pragma unroll
        for (int i = 0; i < 4; i++) {
          Bs[(bn8 + i) * LDSP + krow] = f2bf(f0[i]);
          Bs[(bn8 + 4 + i) * LDSP + krow] = f2bf(f1[i]);
        }
      }
    }
    __syncthreads();
    short8 af[4], bf[4];
#pragma unroll
    for (int i = 0; i < 4; i++)
      af[i] = *(const short8*)&As[(wm + i * 16 + lm) * LDSP + quad * 8];
#pragma unroll
    for (int i = 0; i < 4; i++)
      bf[i] = *(const short8*)&Bs[(wn + i * 16 + lm) * LDSP + quad * 8];
#pragma unroll
    for (int mi = 0; mi < 4; mi++)
#pragma unroll
      for (int ni = 0; ni < 4; ni++)
        acc[mi][ni] = __builtin_amdgcn_mfma_f32_16x16x32_bf16(
            af[mi], bf[ni], acc[mi][ni], 0, 0, 0);
    __syncthreads();
  }

#pragma unroll
  for (int mi = 0; mi < 4; mi++) {
#pragma unroll
    for (int ni = 0; ni < 4; ni++) {
      int col = n0 + wn + ni * 16 + lm;
#pragma unroll
      for (int r = 0; r < 4; r++) {
        int row = m0 + wm + mi * 16 + quad * 4 + r;
        size_t ci = (size_t)row * ldc + col;
        float v = acc[mi][ni][r];
        if (EPI == 4)
          v += (FINAL && !isbf) ? ((const float*)C)[ci] : bf2f(((const ushort*)C)[ci]);
        if (EPI == 2 || EPI == 4) v += ext_ld(bias, biasoff + col, isbf);
        if (EPI == 1) v += ext_ld(res, (size_t)row * ldr + col, isbf);
        if (EPI == 4) v += bf2f(((const ushort*)res)[(size_t)row * ldr + col]);
        if (EPI == 2) v = 0.5f * v * (1.0f + erff(v * 0.70710678118654752f));
        if (FINAL && !isbf) ((float*)C)[ci] = v;
        else                ((ushort*)C)[ci] = f2bf(v);
      }
    }
  }
}

// ---------------- causal flash attention: barrier-free, V^T from global ----
// Per-wave: 16 queries; P in tiny private LDS; K and V^T fragments loaded
// directly from global (V^T materialized by vtrans). NO __syncthreads.
__global__ __launch_bounds__(256) void attn_kernel(
    const ushort* __restrict__ q, const ushort* __restrict__ k,
    const ushort* __restrict__ vT, ushort* __restrict__ ctx) {
  int tid = threadIdx.x, wave = tid >> 6, lane = tid & 63;
  int lm = lane & 15, quad = lane >> 4;
  int bx = blockIdx.x, h = blockIdx.y, b = blockIdx.z;
  int qt = (bx & 1) ? (31 - (bx >> 1)) : (bx >> 1);  // zig-zag balance
  int qw = qt * 64 + wave * 16;
  size_t base = (size_t)b * T_SEQ * D_MODEL + h * 64;
  const ushort* vTh = vT + (size_t)(b * N_HEAD + h) * 64 * T_SEQ;

  __shared__ __align__(16) ushort PlAll[4][16 * PP];
  ushort* Pl = PlAll[wave];

  short8 aq0 = *(const short8*)&q[base + (size_t)(qw + lm) * D_MODEL + quad * 8];
  short8 aq1 = *(const short8*)&q[base + (size_t)(qw + lm) * D_MODEL + 32 + quad * 8];

  floatx4 O[4] = {};
  float mr[4], lr[4];
#pragma unroll
  for (int r = 0; r < 4; r++) { mr[r] = NEG_BIG; lr[r] = 0.f; }

  int ntiles = qt + 1;
  for (int kt = 0; kt < ntiles; ++kt) {
    int k0 = kt * 64;
    floatx4 sc[4];
#pragma unroll
    for (int g = 0; g < 4; g++) {
      const ushort* kr = &k[base + (size_t)(k0 + g * 16 + lm) * D_MODEL + quad * 8];
      short8 bka = *(const short8*)kr;
      short8 bkb = *(const short8*)(kr + 32);
      floatx4 z = {};
      sc[g] = __builtin_amdgcn_mfma_f32_16x16x32_bf16(aq0, bka, z, 0, 0, 0);
      sc[g] = __builtin_amdgcn_mfma_f32_16x16x32_bf16(aq1, bkb, sc[g], 0, 0, 0);
    }
    bool full = (k0 + 63 <= qw);
#pragma unroll
    for (int r = 0; r < 4; r++) {
      int qrow = qw + quad * 4 + r;
      float a[4];
#pragma unroll
      for (int g = 0; g < 4; g++) {
        a[g] = sc[g][r] * 0.125f;
        if (!full && (k0 + g * 16 + lm > qrow)) a[g] = NEG_BIG;
      }
      float tm = fmaxf(fmaxf(a[0], a[1]), fmaxf(a[2], a[3]));
#pragma unroll
      for (int d = 1; d < 16; d <<= 1) tm = fmaxf(tm, __shfl_xor(tm, d, 64));
      float mn = fmaxf(mr[r], tm);
      float alpha = __expf(mr[r] - mn);
      float p[4], rsum = 0.f;
#pragma unroll
      for (int g = 0; g < 4; g++) { p[g] = __expf(a[g] - mn); rsum += p[g]; }
#pragma unroll
      for (int d = 1; d < 16; d <<= 1) rsum += __shfl_xor(rsum, d, 64);
      mr[r] = mn;
      lr[r] = lr[r] * alpha + rsum;
      O[0][r] *= alpha; O[1][r] *= alpha; O[2][r] *= alpha; O[3][r] *= alpha;
#pragma unroll
      for (int g = 0; g < 4; g++)
        Pl[(quad * 4 + r) * PP + g * 16 + lm] = f2bf(p[g]);
    }
    short8 pa0 = *(const short8*)&Pl[lm * PP + quad * 8];
    short8 pa1 = *(const short8*)&Pl[lm * PP + 32 + quad * 8];
#pragma unroll
    for (int d4 = 0; d4 < 4; d4++) {
      const ushort* vr = &vTh[(size_t)(d4 * 16 + lm) * T_SEQ + k0 + quad * 8];
      short8 bv0 = *(const short8*)vr;
      short8 bv1 = *(const short8*)(vr + 32);
      O[d4] = __builtin_amdgcn_mfma_f32_16x16x32_bf16(pa0, bv0, O[d4], 0, 0, 0);
      O[d4] = __builtin_amdgcn_mfma_f32_16x16x32_bf16(pa1, bv1, O[d4], 0, 0, 0);
    }
  }
#pragma unroll
  for (int d4 = 0; d4 < 4; d4++)
#pragma unroll
    for (int r = 0; r < 4; r++) {
      float val = O[d4][r] / fmaxf(lr[r], 1e-20f);
      ctx[base + (size_t)(qw + quad * 4 + r) * D_MODEL + d4 * 16 + lm] = f2bf(val);
    }
}

// ---------------------------------------------------------------------------
extern "C" void kernel_launch(void* const* d_in, const int* in_sizes, int n_in,
                              void* d_out, int out_size, void* d_ws, size_t ws_size,
                              hipStream_t stream) {
  const void* x     = d_in[0];
  const void* ln1_g = d_in[1];
  const void* ln1_b = d_in[2];
  const void* Wq    = d_in[3];
  const void* Wk    = d_in[4];
  const void* Wv    = d_in[5];
  const void* Wo    = d_in[6];
  const void* ln2_g = d_in[7];
  const void* ln2_b = d_in[8];
  const void* W1    = d_in[9];
  const void* b1    = d_in[10];
  const void* W2    = d_in[11];
  const void* b2    = d_in[12];

  const int M = 2 * T_SEQ;  // 4096
  const size_t MEG = 1024 * 1024;
  ushort* W = (ushort*)d_ws;
  ushort* Abuf = W;             // h1 -> ctx -> h2
  ushort* kbuf = W + 4 * MEG;   // k -> x2
  ushort* vbuf = W + 8 * MEG;   // v (dead after vtrans) -> act region start
  ushort* qbuf = (ushort*)d_out;            // q in d_out[0..8MB)
  ushort* vTb  = (ushort*)d_out + 4 * MEG;  // V^T in d_out[8..16MB)

  dim3 blk(256);
  dim3 g18(32, 8);
  dim3 attng(T_SEQ / 64, N_HEAD, 2);
  dim3 vtg(T_SEQ / 32, 2, 32);

  bool fast = ws_size >= (size_t)40 * MEG + 4096;

  if (fast) {
    ushort* WqkvT = W + 12 * MEG;             // dead after QKV
    ushort* WoT   = W + 15 * MEG;             // dead after Wo
    ushort* W1T   = W + 16 * MEG;
    ushort* W2T   = W + 18 * MEG;
    ushort* act   = W + 8 * MEG;              // [4096,2048] over v/WqkvT/WoT
    uint* flag = (uint*)(W + 20 * MEG);

    detect_dtype<<<1, 256, 0, stream>>>((const ushort*)x, flag);

    wconv<<<dim3(32, 32), blk, 0, stream>>>(Wq, WqkvT, 1024, 1024, flag);
    wconv<<<dim3(32, 32), blk, 0, stream>>>(Wk, WqkvT + 1 * MEG, 1024, 1024, flag);
    wconv<<<dim3(32, 32), blk, 0, stream>>>(Wv, WqkvT + 2 * MEG, 1024, 1024, flag);
    wconv<<<dim3(32, 32), blk, 0, stream>>>(Wo, WoT, 1024, 1024, flag);
    wconv<<<dim3(64, 32), blk, 0, stream>>>(W1, W1T, 1024, 2048, flag);
    wconv<<<dim3(32, 64), blk, 0, stream>>>(W2, W2T, 2048, 1024, flag);

    ln_kernel<<<dim3(M), blk, 0, stream>>>(x, ln1_g, ln1_b, Abuf, 1, flag);

    gemm_tt<0, 1><<<dim3(32, 24), blk, 0, stream>>>(
        Abuf, 1024, WqkvT, 1024, qbuf, kbuf, vbuf, 1024,
        nullptr, 0, nullptr, 0, M, 1024, flag);

    vtrans<<<vtg, blk, 0, stream>>>(vbuf, vTb);

    attn_kernel<<<attng, blk, 0, stream>>>(qbuf, kbuf, vTb, Abuf);

    gemm_tt<1, 0><<<g18, blk, 0, stream>>>(
        Abuf, 1024, WoT, 1024, kbuf, nullptr, nullptr, 1024,
        nullptr, 0, x, 1024, M, 1024, flag);

    ln_kernel<<<dim3(M), blk, 0, stream>>>(kbuf, ln2_g, ln2_b, Abuf, 0, flag);

    gemm_tt<2, 0><<<dim3(32, 16), blk, 0, stream>>>(
        Abuf, 1024, W1T, 1024, act, nullptr, nullptr, 2048,
        b1, 0, nullptr, 0, M, 1024, flag);
    gemm_tt<5, 0><<<g18, blk, 0, stream>>>(
        act, 2048, W2T, 2048, d_out, nullptr, nullptr, 1024,
        b2, 0, kbuf, 1024, M, 2048, flag);
  } else {
    uint* flag = (uint*)(W + 12 * MEG);
    detect_dtype<<<1, 256, 0, stream>>>((const ushort*)x, flag);
    ln_kernel<<<dim3(M), blk, 0, stream>>>(x, ln1_g, ln1_b, Abuf, 1, flag);
    gemm_kn<0, 0><<<g18, blk, 0, stream>>>(Abuf, 1024, Wq, 1024, 0, qbuf, 1024,
                                           nullptr, 0, nullptr, 0, M, 1024, flag);
    gemm_kn<0, 0><<<g18, blk, 0, stream>>>(Abuf, 1024, Wk, 1024, 0, kbuf, 1024,
                                           nullptr, 0, nullptr, 0, M, 1024, flag);
    gemm_kn<0, 0><<<g18, blk, 0, stream>>>(Abuf, 1024, Wv, 1024, 0, vbuf, 1024,
                                           nullptr, 0, nullptr, 0, M, 1024, flag);
    vtrans<<<vtg, blk, 0, stream>>>(vbuf, vTb);
    attn_kernel<<<attng, blk, 0, stream>>>(qbuf, kbuf, vTb, Abuf);
    gemm_kn<1, 0><<<g18, blk, 0, stream>>>(Abuf, 1024, Wo, 1024, 0, kbuf, 1024,
                                           nullptr, 0, x, 1024, M, 1024, flag);
    ln_kernel<<<dim3(M), blk, 0, stream>>>(kbuf, ln2_g, ln2_b, Abuf, 0, flag);
    gemm_kn<2, 0><<<g18, blk, 0, stream>>>(Abuf, 1024, W1, 2048, 0, vbuf, 1024,
                                           b1, 0, nullptr, 0, M, 1024, flag);
    gemm_kn<0, 1><<<g18, blk, 0, stream>>>(vbuf, 1024, W2, 1024, 0, d_out, 1024,
                                           nullptr, 0, nullptr, 0, M, 1024, flag);
    gemm_kn<2, 0><<<g18, blk, 0, stream>>>(Abuf, 1024, W1, 2048, 1024, vbuf, 1024,
                                           b1, 1024, nullptr, 0, M, 1024, flag);
    gemm_kn<4, 1><<<g18, blk, 0, stream>>>(vbuf, 1024, W2, 1024, (size_t)1024 * 1024,
                                           d_out, 1024, b2, 0, kbuf, 1024, M, 1024, flag);
  }
}

// Round 10
// 476.217 us; speedup vs baseline: 1.2052x; 1.1510x over previous
//
#include <hip/hip_runtime.h>
#include <hip/hip_bf16.h>

typedef __attribute__((ext_vector_type(8))) short short8;
typedef __attribute__((ext_vector_type(4))) float floatx4;
typedef __attribute__((ext_vector_type(4))) unsigned int uintx4;

#define D_MODEL 1024
#define T_SEQ   2048
#define N_HEAD  16
#define NEG_BIG (-1e30f)
#define BK 32
#define LDSP 40 // fallback-gemm pitch
#define VP 72   // V-tile pitch: 144B rows, 16B-aligned -> true ds_read_b128
#define PP 72   // P-tile pitch

static __device__ __forceinline__ float bf2f(ushort u) {
  unsigned int x = ((unsigned int)u) << 16;
  return __builtin_bit_cast(float, x);
}
static __device__ __forceinline__ ushort san(ushort u) {
  return ((u & 0x7F80u) == 0x7F80u) ? (ushort)0 : u;
}
static __device__ __forceinline__ float bf2f_s(ushort u) { return bf2f(san(u)); }
static __device__ __forceinline__ ushort f2bf(float f) {
  unsigned int x = __builtin_bit_cast(unsigned int, f);
  x += 0x7FFFu + ((x >> 16) & 1u);
  return (ushort)(x >> 16);
}
static __device__ __forceinline__ float ext_ld(const void* p, size_t i, int isbf) {
  return isbf ? bf2f_s(((const ushort*)p)[i]) : ((const float*)p)[i];
}
// async global->LDS DMA, 16 B/lane; LDS dest = wave-uniform base + lane*16
static __device__ __forceinline__ void gload16(const void* g, void* l) {
  __builtin_amdgcn_global_load_lds(
      (const __attribute__((address_space(1))) void*)g,
      (__attribute__((address_space(3))) void*)l, 16, 0, 0);
}

// dtype probe: low ushort of dword -> bf16 data has exp in [0x60,0x8F] ~100%
__global__ void detect_dtype(const ushort* x, uint* flag) {
  int tid = threadIdx.x;
  int cnt = 0;
  for (int j = 0; j < 16; j++) {
    ushort u = x[2 * (tid * 16 + j)];
    int e = (u >> 7) & 0xFF;
    if (e >= 0x60 && e <= 0x8F) cnt++;
  }
  for (int d = 32; d; d >>= 1) cnt += __shfl_xor(cnt, d, 64);
  __shared__ int c[4];
  if ((tid & 63) == 0) c[tid >> 6] = cnt;
  __syncthreads();
  if (tid == 0) flag[0] = (c[0] + c[1] + c[2] + c[3] >= 2048) ? 1u : 0u;
}

// weight convert+transpose: in[R,C] (ext dtype) -> out[C,R] bf16
__global__ __launch_bounds__(256) void wconv(
    const void* __restrict__ in, ushort* __restrict__ out, int R, int C,
    const uint* __restrict__ flagp) {
  int isbf = (int)*flagp;
  __shared__ float t[32][33];
  int tx = threadIdx.x & 31, ty = threadIdx.x >> 5;
  int c0 = blockIdx.x * 32, r0 = blockIdx.y * 32;
  for (int i = ty; i < 32; i += 8)
    t[i][tx] = ext_ld(in, (size_t)(r0 + i) * C + c0 + tx, isbf);
  __syncthreads();
  for (int i = ty; i < 32; i += 8)
    out[(size_t)(c0 + i) * R + r0 + tx] = f2bf(t[tx][i]);
}

// ---------------- LayerNorm -> bf16 ----------------
__global__ __launch_bounds__(256) void ln_kernel(
    const void* __restrict__ x, const void* __restrict__ g,
    const void* __restrict__ bb, ushort* __restrict__ out,
    int ext, const uint* __restrict__ flagp) {
  int wbf = (int)*flagp;
  int xbf = ext ? wbf : 1;
  int row = blockIdx.x, tid = threadIdx.x;
  size_t ro = (size_t)row * D_MODEL;
  float v[4], gv[4], bv[4];
  if (!xbf) {
    floatx4 xv = *((const floatx4*)((const float*)x + ro) + tid);
#pragma unroll
    for (int i = 0; i < 4; i++) v[i] = xv[i];
  } else {
#pragma unroll
    for (int i = 0; i < 4; i++) v[i] = bf2f_s(((const ushort*)x)[ro + tid * 4 + i]);
  }
  float s = 0.f, sq = 0.f;
#pragma unroll
  for (int i = 0; i < 4; i++) { s += v[i]; sq += v[i] * v[i]; }
#pragma unroll
  for (int d = 32; d; d >>= 1) {
    s += __shfl_xor(s, d, 64);
    sq += __shfl_xor(sq, d, 64);
  }
  __shared__ float red[8];
  int wave = tid >> 6, lane = tid & 63;
  if (lane == 0) { red[wave] = s; red[4 + wave] = sq; }
  __syncthreads();
  s = red[0] + red[1] + red[2] + red[3];
  sq = red[4] + red[5] + red[6] + red[7];
  float mu = s * (1.0f / D_MODEL);
  float var = sq * (1.0f / D_MODEL) - mu * mu;
  float rs = rsqrtf(fmaxf(var, 0.f) + 1e-5f);
  if (!wbf) {
    floatx4 g4 = *((const floatx4*)g + tid);
    floatx4 b4 = *((const floatx4*)bb + tid);
#pragma unroll
    for (int i = 0; i < 4; i++) { gv[i] = g4[i]; bv[i] = b4[i]; }
  } else {
#pragma unroll
    for (int i = 0; i < 4; i++) {
      gv[i] = bf2f_s(((const ushort*)g)[tid * 4 + i]);
      bv[i] = bf2f_s(((const ushort*)bb)[tid * 4 + i]);
    }
  }
  ushort o4[4];
#pragma unroll
  for (int i = 0; i < 4; i++) o4[i] = f2bf((v[i] - mu) * rs * gv[i] + bv[i]);
  *(uint2*)(out + ro + tid * 4) = *(uint2*)o4;
}

// ---------------- fast GEMM: C = A[M,K] @ Bt[N,K]^T, both bf16 --------------
// EPI: 0 plain bf16 | 1 +res(ext) bf16 | 2 +bias(ext)+GELU bf16 |
//      5 +bias(ext)+res(bf16) -> store FINAL dtype
template <int EPI, int SPLIT>
__global__ __launch_bounds__(256) void gemm_tt(
    const ushort* __restrict__ A, int lda,
    const ushort* __restrict__ Bt, int ldbt,
    void* __restrict__ C0v, ushort* __restrict__ C1, ushort* __restrict__ C2,
    int ldc,
    const void* __restrict__ bias, size_t biasoff,
    const void* __restrict__ res, int ldr,
    int M, int K, const uint* __restrict__ flagp) {
  __shared__ __align__(16) ushort As[128 * 32];
  __shared__ __align__(16) ushort Bs[128 * 32];
  int isbf = (int)*flagp;
  int tid = threadIdx.x;
  int wave = tid >> 6, lane = tid & 63, lm = lane & 15, quad = lane >> 4;
  int m0 = blockIdx.x * 128, n0 = blockIdx.y * 128;
  int wm = (wave >> 1) * 64, wn = (wave & 1) * 64;
  floatx4 acc[4][4] = {};
  int sr = tid >> 2;
  int sc = (tid & 3) * 8;
  ushort* lA0 = &As[(wave * 16) * 32];
  ushort* lA1 = &As[(64 + wave * 16) * 32];
  ushort* lB0 = &Bs[(wave * 16) * 32];
  ushort* lB1 = &Bs[(64 + wave * 16) * 32];

  for (int kk = 0; kk < K; kk += BK) {
    gload16(A + (size_t)(m0 + sr) * lda + kk + sc, lA0);
    gload16(A + (size_t)(m0 + sr + 64) * lda + kk + sc, lA1);
    gload16(Bt + (size_t)(n0 + sr) * ldbt + kk + sc, lB0);
    gload16(Bt + (size_t)(n0 + sr + 64) * ldbt + kk + sc, lB1);
    __syncthreads();
    short8 af[4], bf[4];
#pragma unroll
    for (int i = 0; i < 4; i++)
      af[i] = *(const short8*)&As[(wm + i * 16 + lm) * 32 + quad * 8];
#pragma unroll
    for (int i = 0; i < 4; i++)
      bf[i] = *(const short8*)&Bs[(wn + i * 16 + lm) * 32 + quad * 8];
#pragma unroll
    for (int mi = 0; mi < 4; mi++)
#pragma unroll
      for (int ni = 0; ni < 4; ni++)
        acc[mi][ni] = __builtin_amdgcn_mfma_f32_16x16x32_bf16(
            af[mi], bf[ni], acc[mi][ni], 0, 0, 0);
    __syncthreads();
  }

  ushort* Cseg = (ushort*)C0v;
  int colbase = n0;
  if (SPLIT) {
    int seg = n0 >> 10;
    Cseg = (seg == 0) ? (ushort*)C0v : (seg == 1 ? C1 : C2);
    colbase = n0 & 1023;
  }
#pragma unroll
  for (int mi = 0; mi < 4; mi++) {
#pragma unroll
    for (int ni = 0; ni < 4; ni++) {
      int col = colbase + wn + ni * 16 + lm;
#pragma unroll
      for (int r = 0; r < 4; r++) {
        int row = m0 + wm + mi * 16 + quad * 4 + r;
        size_t ci = (size_t)row * ldc + col;
        float v = acc[mi][ni][r];
        if (EPI == 2 || EPI == 5) v += ext_ld(bias, biasoff + col, isbf);
        if (EPI == 1) v += ext_ld(res, (size_t)row * ldr + col, isbf);
        if (EPI == 5) v += bf2f(((const ushort*)res)[(size_t)row * ldr + col]);
        if (EPI == 2) v = 0.5f * v * (1.0f + erff(v * 0.70710678118654752f));
        if (EPI == 5 && !isbf) ((float*)C0v)[ci] = v;
        else                   Cseg[ci] = f2bf(v);
      }
    }
  }
}

// ---------------- fallback GEMM: B in [K,N] external dtype ------------------
template <int EPI, int FINAL>
__global__ __launch_bounds__(256) void gemm_kn(
    const ushort* __restrict__ A, int lda,
    const void* __restrict__ B, int ldb, size_t boff,
    void* __restrict__ C, int ldc,
    const void* __restrict__ bias, size_t biasoff,
    const void* __restrict__ res, int ldr,
    int M, int K, const uint* __restrict__ flagp) {
  __shared__ __align__(16) ushort As[128 * LDSP];
  __shared__ __align__(16) ushort Bs[128 * LDSP];
  int isbf = (int)*flagp;
  int tid = threadIdx.x;
  int wave = tid >> 6, lane = tid & 63, lm = lane & 15, quad = lane >> 4;
  int m0 = blockIdx.x * 128, n0 = blockIdx.y * 128;
  int wm = (wave >> 1) * 64, wn = (wave & 1) * 64;
  floatx4 acc[4][4] = {};
  int sr = tid >> 2;
  int sc = (tid & 3) * 8;
  int bk = tid >> 4;
  int bn8 = (tid & 15) * 8;

  for (int kk = 0; kk < K; kk += BK) {
    uintx4 va0 = *(const uintx4*)(A + (size_t)(m0 + sr) * lda + kk + sc);
    uintx4 va1 = *(const uintx4*)(A + (size_t)(m0 + sr + 64) * lda + kk + sc);
    *(uintx4*)&As[sr * LDSP + sc] = va0;
    *(uintx4*)&As[(sr + 64) * LDSP + sc] = va1;
    if (isbf) {
      const ushort* Bu = (const ushort*)B;
#pragma unroll
      for (int p = 0; p < 2; p++) {
        int krow = bk + p * 16;
        uintx4 raw = *(const uintx4*)(Bu + boff + (size_t)(kk + krow) * ldb + n0 + bn8);
        ushort tmp[8] __attribute__((aligned(16)));
        *(uintx4*)tmp = raw;
#pragma unroll
        for (int i = 0; i < 8; i++) Bs[(bn8 + i) * LDSP + krow] = san(tmp[i]);
      }
    } else {
      const float* Bf = (const float*)B;
#pragma unroll
      for (int p = 0; p < 2; p++) {
        int krow = bk + p * 16;
        const float* src = Bf + boff + (size_t)(kk + krow) * ldb + n0 + bn8;
        floatx4 f0 = *(const floatx4*)src;
        floatx4 f1 = *(const floatx4*)(src + 4);
#pragma unroll
        for (int i = 0; i < 4; i++) {
          Bs[(bn8 + i) * LDSP + krow] = f2bf(f0[i]);
          Bs[(bn8 + 4 + i) * LDSP + krow] = f2bf(f1[i]);
        }
      }
    }
    __syncthreads();
    short8 af[4], bf[4];
#pragma unroll
    for (int i = 0; i < 4; i++)
      af[i] = *(const short8*)&As[(wm + i * 16 + lm) * LDSP + quad * 8];
#pragma unroll
    for (int i = 0; i < 4; i++)
      bf[i] = *(const short8*)&Bs[(wn + i * 16 + lm) * LDSP + quad * 8];
#pragma unroll
    for (int mi = 0; mi < 4; mi++)
#pragma unroll
      for (int ni = 0; ni < 4; ni++)
        acc[mi][ni] = __builtin_amdgcn_mfma_f32_16x16x32_bf16(
            af[mi], bf[ni], acc[mi][ni], 0, 0, 0);
    __syncthreads();
  }

#pragma unroll
  for (int mi = 0; mi < 4; mi++) {
#pragma unroll
    for (int ni = 0; ni < 4; ni++) {
      int col = n0 + wn + ni * 16 + lm;
#pragma unroll
      for (int r = 0; r < 4; r++) {
        int row = m0 + wm + mi * 16 + quad * 4 + r;
        size_t ci = (size_t)row * ldc + col;
        float v = acc[mi][ni][r];
        if (EPI == 4)
          v += (FINAL && !isbf) ? ((const float*)C)[ci] : bf2f(((const ushort*)C)[ci]);
        if (EPI == 2 || EPI == 4) v += ext_ld(bias, biasoff + col, isbf);
        if (EPI == 1) v += ext_ld(res, (size_t)row * ldr + col, isbf);
        if (EPI == 4) v += bf2f(((const ushort*)res)[(size_t)row * ldr + col]);
        if (EPI == 2) v = 0.5f * v * (1.0f + erff(v * 0.70710678118654752f));
        if (FINAL && !isbf) ((float*)C)[ci] = v;
        else                ((ushort*)C)[ci] = f2bf(v);
      }
    }
  }
}

// ---------------- causal flash attention: shared V staging + reg prefetch ---
// 64q x 64k tiles, 4 waves. Next tile's V rows + K frags prefetched into
// registers during current tile's softmax/PV (consumed after 2 barriers).
__global__ __launch_bounds__(256) void attn_kernel(
    const ushort* __restrict__ q, const ushort* __restrict__ k,
    const ushort* __restrict__ v, ushort* __restrict__ ctx) {
  int tid = threadIdx.x, wave = tid >> 6, lane = tid & 63;
  int lm = lane & 15, quad = lane >> 4;
  int bx = blockIdx.x, h = blockIdx.y, b = blockIdx.z;
  int qt = (bx & 1) ? (31 - (bx >> 1)) : (bx >> 1);  // zig-zag balance
  int qw = qt * 64 + wave * 16;
  size_t base = (size_t)b * T_SEQ * D_MODEL + h * 64;

  __shared__ __align__(16) ushort Vst[64 * VP];      // [hd][key]
  __shared__ __align__(16) ushort PlAll[4][16 * PP]; // per-wave P
  ushort* Pl = PlAll[wave];

  short8 aq0 = *(const short8*)&q[base + (size_t)(qw + lm) * D_MODEL + quad * 8];
  short8 aq1 = *(const short8*)&q[base + (size_t)(qw + lm) * D_MODEL + 32 + quad * 8];

  floatx4 O[4] = {};
  float mr[4], lr[4];
#pragma unroll
  for (int r = 0; r < 4; r++) { mr[r] = NEG_BIG; lr[r] = 0.f; }

  int ntiles = qt + 1;
  int vr_r = tid & 63, vcg = (tid >> 6) * 16;
  const ushort* vrow = v + base + vcg;

  // prefetch tile 0
  uintx4 vv0 = *(const uintx4*)(vrow + (size_t)vr_r * D_MODEL);
  uintx4 vv1 = *(const uintx4*)(vrow + (size_t)vr_r * D_MODEL + 8);
  short8 kfa[4], kfb[4];
#pragma unroll
  for (int g = 0; g < 4; g++) {
    const ushort* kr = &k[base + (size_t)(g * 16 + lm) * D_MODEL + quad * 8];
    kfa[g] = *(const short8*)kr;
    kfb[g] = *(const short8*)(kr + 32);
  }

  for (int kt = 0; kt < ntiles; ++kt) {
    int k0 = kt * 64;
    // scatter prefetched V into shared Vst (all 256 threads)
    {
      ushort t0[8] __attribute__((aligned(16)));
      ushort t1[8] __attribute__((aligned(16)));
      *(uintx4*)t0 = vv0;
      *(uintx4*)t1 = vv1;
#pragma unroll
      for (int i = 0; i < 8; i++) {
        Vst[(vcg + i) * VP + vr_r] = t0[i];
        Vst[(vcg + 8 + i) * VP + vr_r] = t1[i];
      }
    }
    // QK from prefetched K frags
    floatx4 sc[4];
#pragma unroll
    for (int g = 0; g < 4; g++) {
      floatx4 z = {};
      sc[g] = __builtin_amdgcn_mfma_f32_16x16x32_bf16(aq0, kfa[g], z, 0, 0, 0);
      sc[g] = __builtin_amdgcn_mfma_f32_16x16x32_bf16(aq1, kfb[g], sc[g], 0, 0, 0);
    }
    // issue prefetch for next tile (consumed after 2 barriers)
    int k0n = (kt + 1 < ntiles) ? k0 + 64 : k0;
    uintx4 nv0 = *(const uintx4*)(vrow + (size_t)(k0n + vr_r) * D_MODEL);
    uintx4 nv1 = *(const uintx4*)(vrow + (size_t)(k0n + vr_r) * D_MODEL + 8);
    short8 nka[4], nkb[4];
#pragma unroll
    for (int g = 0; g < 4; g++) {
      const ushort* kr = &k[base + (size_t)(k0n + g * 16 + lm) * D_MODEL + quad * 8];
      nka[g] = *(const short8*)kr;
      nkb[g] = *(const short8*)(kr + 32);
    }
    // online softmax
    bool full = (k0 + 63 <= qw);
#pragma unroll
    for (int r = 0; r < 4; r++) {
      int qrow = qw + quad * 4 + r;
      float a[4];
#pragma unroll
      for (int g = 0; g < 4; g++) {
        a[g] = sc[g][r] * 0.125f;
        if (!full && (k0 + g * 16 + lm > qrow)) a[g] = NEG_BIG;
      }
      float tm = fmaxf(fmaxf(a[0], a[1]), fmaxf(a[2], a[3]));
#pragma unroll
      for (int d = 1; d < 16; d <<= 1) tm = fmaxf(tm, __shfl_xor(tm, d, 64));
      float mn = fmaxf(mr[r], tm);
      float alpha = __expf(mr[r] - mn);
      float p[4], rsum = 0.f;
#pragma unroll
      for (int g = 0; g < 4; g++) { p[g] = __expf(a[g] - mn); rsum += p[g]; }
#pragma unroll
      for (int d = 1; d < 16; d <<= 1) rsum += __shfl_xor(rsum, d, 64);
      mr[r] = mn;
      lr[r] = lr[r] * alpha + rsum;
      O[0][r] *= alpha; O[1][r] *= alpha; O[2][r] *= alpha; O[3][r] *= alpha;
#pragma unroll
      for (int g = 0; g < 4; g++)
        Pl[(quad * 4 + r) * PP + g * 16 + lm] = f2bf(p[g]);
    }
    __syncthreads();   // Vst scatter complete (block-wide)
    short8 pa0 = *(const short8*)&Pl[lm * PP + quad * 8];
    short8 pa1 = *(const short8*)&Pl[lm * PP + 32 + quad * 8];
#pragma unroll
    for (int d4 = 0; d4 < 4; d4++) {
      short8 bv0 = *(const short8*)&Vst[(d4 * 16 + lm) * VP + quad * 8];
      short8 bv1 = *(const short8*)&Vst[(d4 * 16 + lm) * VP + 32 + quad * 8];
      O[d4] = __builtin_amdgcn_mfma_f32_16x16x32_bf16(pa0, bv0, O[d4], 0, 0, 0);
      O[d4] = __builtin_amdgcn_mfma_f32_16x16x32_bf16(pa1, bv1, O[d4], 0, 0, 0);
    }
    __syncthreads();   // protect Vst before next scatter
    vv0 = nv0; vv1 = nv1;
#pragma unroll
    for (int g = 0; g < 4; g++) { kfa[g] = nka[g]; kfb[g] = nkb[g]; }
  }
#pragma unroll
  for (int d4 = 0; d4 < 4; d4++)
#pragma unroll
    for (int r = 0; r < 4; r++) {
      float val = O[d4][r] / fmaxf(lr[r], 1e-20f);
      ctx[base + (size_t)(qw + quad * 4 + r) * D_MODEL + d4 * 16 + lm] = f2bf(val);
    }
}

// ---------------------------------------------------------------------------
extern "C" void kernel_launch(void* const* d_in, const int* in_sizes, int n_in,
                              void* d_out, int out_size, void* d_ws, size_t ws_size,
                              hipStream_t stream) {
  const void* x     = d_in[0];
  const void* ln1_g = d_in[1];
  const void* ln1_b = d_in[2];
  const void* Wq    = d_in[3];
  const void* Wk    = d_in[4];
  const void* Wv    = d_in[5];
  const void* Wo    = d_in[6];
  const void* ln2_g = d_in[7];
  const void* ln2_b = d_in[8];
  const void* W1    = d_in[9];
  const void* b1    = d_in[10];
  const void* W2    = d_in[11];
  const void* b2    = d_in[12];

  const int M = 2 * T_SEQ;  // 4096
  const size_t MEG = 1024 * 1024;
  ushort* W = (ushort*)d_ws;
  ushort* Abuf = W;             // h1 -> ctx -> h2
  ushort* kbuf = W + 4 * MEG;   // k -> x2
  ushort* vbuf = W + 8 * MEG;   // v -> act region start
  ushort* qbuf = (ushort*)d_out;

  dim3 blk(256);
  dim3 g18(32, 8);
  dim3 attng(T_SEQ / 64, N_HEAD, 2);

  bool fast = ws_size >= (size_t)40 * MEG + 4096;

  if (fast) {
    ushort* WqkvT = W + 12 * MEG;             // dead after QKV
    ushort* WoT   = W + 15 * MEG;             // dead after Wo
    ushort* W1T   = W + 16 * MEG;
    ushort* W2T   = W + 18 * MEG;
    ushort* act   = W + 8 * MEG;              // [4096,2048] over v/WqkvT/WoT
    uint* flag = (uint*)(W + 20 * MEG);

    detect_dtype<<<1, 256, 0, stream>>>((const ushort*)x, flag);

    wconv<<<dim3(32, 32), blk, 0, stream>>>(Wq, WqkvT, 1024, 1024, flag);
    wconv<<<dim3(32, 32), blk, 0, stream>>>(Wk, WqkvT + 1 * MEG, 1024, 1024, flag);
    wconv<<<dim3(32, 32), blk, 0, stream>>>(Wv, WqkvT + 2 * MEG, 1024, 1024, flag);
    wconv<<<dim3(32, 32), blk, 0, stream>>>(Wo, WoT, 1024, 1024, flag);
    wconv<<<dim3(64, 32), blk, 0, stream>>>(W1, W1T, 1024, 2048, flag);
    wconv<<<dim3(32, 64), blk, 0, stream>>>(W2, W2T, 2048, 1024, flag);

    ln_kernel<<<dim3(M), blk, 0, stream>>>(x, ln1_g, ln1_b, Abuf, 1, flag);

    gemm_tt<0, 1><<<dim3(32, 24), blk, 0, stream>>>(
        Abuf, 1024, WqkvT, 1024, qbuf, kbuf, vbuf, 1024,
        nullptr, 0, nullptr, 0, M, 1024, flag);

    attn_kernel<<<attng, blk, 0, stream>>>(qbuf, kbuf, vbuf, Abuf);

    gemm_tt<1, 0><<<g18, blk, 0, stream>>>(
        Abuf, 1024, WoT, 1024, kbuf, nullptr, nullptr, 1024,
        nullptr, 0, x, 1024, M, 1024, flag);

    ln_kernel<<<dim3(M), blk, 0, stream>>>(kbuf, ln2_g, ln2_b, Abuf, 0, flag);

    gemm_tt<2, 0><<<dim3(32, 16), blk, 0, stream>>>(
        Abuf, 1024, W1T, 1024, act, nullptr, nullptr, 2048,
        b1, 0, nullptr, 0, M, 1024, flag);
    gemm_tt<5, 0><<<g18, blk, 0, stream>>>(
        act, 2048, W2T, 2048, d_out, nullptr, nullptr, 1024,
        b2, 0, kbuf, 1024, M, 2048, flag);
  } else {
    uint* flag = (uint*)(W + 12 * MEG);
    detect_dtype<<<1, 256, 0, stream>>>((const ushort*)x, flag);
    ln_kernel<<<dim3(M), blk, 0, stream>>>(x, ln1_g, ln1_b, Abuf, 1, flag);
    gemm_kn<0, 0><<<g18, blk, 0, stream>>>(Abuf, 1024, Wq, 1024, 0, qbuf, 1024,
                                           nullptr, 0, nullptr, 0, M, 1024, flag);
    gemm_kn<0, 0><<<g18, blk, 0, stream>>>(Abuf, 1024, Wk, 1024, 0, kbuf, 1024,
                                           nullptr, 0, nullptr, 0, M, 1024, flag);
    gemm_kn<0, 0><<<g18, blk, 0, stream>>>(Abuf, 1024, Wv, 1024, 0, vbuf, 1024,
                                           nullptr, 0, nullptr, 0, M, 1024, flag);
    attn_kernel<<<attng, blk, 0, stream>>>(qbuf, kbuf, vbuf, Abuf);
    gemm_kn<1, 0><<<g18, blk, 0, stream>>>(Abuf, 1024, Wo, 1024, 0, kbuf, 1024,
                                           nullptr, 0, x, 1024, M, 1024, flag);
    ln_kernel<<<dim3(M), blk, 0, stream>>>(kbuf, ln2_g, ln2_b, Abuf, 0, flag);
    gemm_kn<2, 0><<<g18, blk, 0, stream>>>(Abuf, 1024, W1, 2048, 0, vbuf, 1024,
                                           b1, 0, nullptr, 0, M, 1024, flag);
    gemm_kn<0, 1><<<g18, blk, 0, stream>>>(vbuf, 1024, W2, 1024, 0, d_out, 1024,
                                           nullptr, 0, nullptr, 0, M, 1024, flag);
    gemm_kn<2, 0><<<g18, blk, 0, stream>>>(Abuf, 1024, W1, 2048, 1024, vbuf, 1024,
                                           b1, 1024, nullptr, 0, M, 1024, flag);
    gemm_kn<4, 1><<<g18, blk, 0, stream>>>(vbuf, 1024, W2, 1024, (size_t)1024 * 1024,
                                           d_out, 1024, b2, 0, kbuf, 1024, M, 1024, flag);
  }
}